// Round 1
// baseline (977.994 us; speedup 1.0000x reference)
//
#include <hip/hip_runtime.h>
#include <math.h>

#define N_NODES 100000
#define EPS 1e-5f

// ---------------- CSR build ----------------
__global__ void hist_kernel(const int* __restrict__ dst, int E, int* __restrict__ cnt) {
    int e = blockIdx.x * blockDim.x + threadIdx.x;
    if (e < E) atomicAdd(&cnt[dst[e]], 1);
}

__global__ void scan1_kernel(const int* __restrict__ cnt, int n, int* __restrict__ bsum) {
    __shared__ int s[256];
    int i = blockIdx.x * 256 + threadIdx.x;
    s[threadIdx.x] = (i < n) ? cnt[i] : 0;
    __syncthreads();
    for (int off = 128; off > 0; off >>= 1) {
        if (threadIdx.x < off) s[threadIdx.x] += s[threadIdx.x + off];
        __syncthreads();
    }
    if (threadIdx.x == 0) bsum[blockIdx.x] = s[0];
}

__global__ void scan2_kernel(const int* __restrict__ bsum, int nb, int* __restrict__ bpre,
                             int* __restrict__ row_ptr, int n, int E) {
    __shared__ int s[512];
    int t = threadIdx.x;
    s[t] = (t < nb) ? bsum[t] : 0;
    __syncthreads();
    for (int off = 1; off < 512; off <<= 1) {
        int v = (t >= off) ? s[t - off] : 0;
        __syncthreads();
        s[t] += v;
        __syncthreads();
    }
    if (t < nb) bpre[t] = (t == 0) ? 0 : s[t - 1];
    if (t == 0) row_ptr[n] = E;
}

__global__ void scan3_kernel(const int* __restrict__ cnt, int n, const int* __restrict__ bpre,
                             int* __restrict__ row_ptr) {
    __shared__ int s[256];
    int i = blockIdx.x * 256 + threadIdx.x;
    int t = threadIdx.x;
    int v = (i < n) ? cnt[i] : 0;
    s[t] = v;
    __syncthreads();
    for (int off = 1; off < 256; off <<= 1) {
        int u = (t >= off) ? s[t - off] : 0;
        __syncthreads();
        s[t] += u;
        __syncthreads();
    }
    if (i < n) row_ptr[i] = bpre[blockIdx.x] + s[t] - v;  // exclusive prefix
}

__global__ void scatter_kernel(const int* __restrict__ src, const int* __restrict__ dst, int E,
                               const int* __restrict__ row_ptr, int* __restrict__ fill,
                               int* __restrict__ col) {
    int e = blockIdx.x * blockDim.x + threadIdx.x;
    if (e < E) {
        int v = dst[e];
        int p = row_ptr[v] + atomicAdd(&fill[v], 1);
        col[p] = src[e];
    }
}

// ---------------- mean aggregation: one wave per node ----------------
template <int D>
__global__ void agg_kernel(const float* __restrict__ h, const int* __restrict__ row_ptr,
                           const int* __restrict__ col, float* __restrict__ mean, int n) {
    int wid = (blockIdx.x * blockDim.x + threadIdx.x) >> 6;
    int lane = threadIdx.x & 63;
    if (wid >= n) return;
    int start = row_ptr[wid], end = row_ptr[wid + 1];
    float inv = 1.f / fmaxf((float)(end - start), 1.f);
    if constexpr (D == 128) {
        float2 acc = {0.f, 0.f};
        int p = start;
        for (; p + 4 <= end; p += 4) {
            int s0 = col[p], s1 = col[p + 1], s2 = col[p + 2], s3 = col[p + 3];
            float2 a = *(const float2*)&h[(size_t)s0 * 128 + lane * 2];
            float2 b = *(const float2*)&h[(size_t)s1 * 128 + lane * 2];
            float2 c = *(const float2*)&h[(size_t)s2 * 128 + lane * 2];
            float2 d = *(const float2*)&h[(size_t)s3 * 128 + lane * 2];
            acc.x += a.x + b.x + c.x + d.x;
            acc.y += a.y + b.y + c.y + d.y;
        }
        for (; p < end; ++p) {
            float2 a = *(const float2*)&h[(size_t)col[p] * 128 + lane * 2];
            acc.x += a.x;
            acc.y += a.y;
        }
        mean[(size_t)wid * 128 + lane * 2] = acc.x * inv;
        mean[(size_t)wid * 128 + lane * 2 + 1] = acc.y * inv;
    } else if constexpr (D == 64) {
        float acc = 0.f;
        int p = start;
        for (; p + 4 <= end; p += 4) {
            int s0 = col[p], s1 = col[p + 1], s2 = col[p + 2], s3 = col[p + 3];
            acc += h[(size_t)s0 * 64 + lane] + h[(size_t)s1 * 64 + lane] +
                   h[(size_t)s2 * 64 + lane] + h[(size_t)s3 * 64 + lane];
        }
        for (; p < end; ++p) acc += h[(size_t)col[p] * 64 + lane];
        mean[(size_t)wid * 64 + lane] = acc * inv;
    } else {  // D == 9
        if (lane < 9) {
            float acc = 0.f;
            for (int p = start; p < end; ++p) acc += h[(size_t)col[p] * 9 + lane];
            mean[(size_t)wid * 9 + lane] = acc * inv;
        }
    }
}

// ---------------- weight transpose: wt[k][j], k in [0,2*din) ----------------
__global__ void wtrans_kernel(const float* __restrict__ wl, const float* __restrict__ wr,
                              int din, int dout, float* __restrict__ wt) {
    int i = blockIdx.x * blockDim.x + threadIdx.x;
    int K2 = 2 * din;
    if (i >= K2 * dout) return;
    int k = i / dout, j = i % dout;
    wt[k * dout + j] = (k < din) ? wl[j * din + k] : wr[j * din + (k - din)];
}

// ---------------- fused linear (concat-K GEMM) + LayerNorm + optional ReLU ----
template <int DIN, int DOUT, bool RELU>
__global__ __launch_bounds__(256) void linear_ln_kernel(
    const float* __restrict__ meanp, const float* __restrict__ hp,
    const float* __restrict__ wt, const float* __restrict__ bias,
    const float* __restrict__ g, const float* __restrict__ be,
    float* __restrict__ out, int n) {
    constexpr int K2 = 2 * DIN;
    constexpr int NCOL = DOUT / 4;           // thread cols (4 outputs each)
    constexpr int NROW = 256 / NCOL;         // thread rows (4 nodes each)
    constexpr int TN = 4 * NROW;             // nodes per block
    constexpr int ASTR = TN + 4;             // padded LDS stride (16B-aligned)
    constexpr int OSTR = DOUT + 4;
    constexpr int SMEMF = (K2 * ASTR > TN * OSTR) ? K2 * ASTR : TN * OSTR;
    __shared__ float smem[SMEMF];

    int tid = threadIdx.x;
    int n0base = blockIdx.x * TN;

    // stage A' = [mean | h] transposed: smem[k][node]
    for (int idx = tid; idx < TN * K2; idx += 256) {
        int nn = idx / K2;
        int k = idx % K2;
        int node = n0base + nn;
        float v = 0.f;
        if (node < n)
            v = (k < DIN) ? meanp[(size_t)node * DIN + k] : hp[(size_t)node * DIN + (k - DIN)];
        smem[k * ASTR + nn] = v;
    }
    __syncthreads();

    int colt = tid % NCOL;
    int rowt = tid / NCOL;
    int j0 = colt * 4;
    int nn0 = rowt * 4;

    float acc[4][4];
#pragma unroll
    for (int i = 0; i < 4; ++i)
#pragma unroll
        for (int j = 0; j < 4; ++j) acc[i][j] = 0.f;

#pragma unroll 4
    for (int k = 0; k < K2; ++k) {
        float4 a = *(const float4*)&smem[k * ASTR + nn0];
        float4 w = *(const float4*)&wt[k * DOUT + j0];
        acc[0][0] = fmaf(a.x, w.x, acc[0][0]);
        acc[0][1] = fmaf(a.x, w.y, acc[0][1]);
        acc[0][2] = fmaf(a.x, w.z, acc[0][2]);
        acc[0][3] = fmaf(a.x, w.w, acc[0][3]);
        acc[1][0] = fmaf(a.y, w.x, acc[1][0]);
        acc[1][1] = fmaf(a.y, w.y, acc[1][1]);
        acc[1][2] = fmaf(a.y, w.z, acc[1][2]);
        acc[1][3] = fmaf(a.y, w.w, acc[1][3]);
        acc[2][0] = fmaf(a.z, w.x, acc[2][0]);
        acc[2][1] = fmaf(a.z, w.y, acc[2][1]);
        acc[2][2] = fmaf(a.z, w.z, acc[2][2]);
        acc[2][3] = fmaf(a.z, w.w, acc[2][3]);
        acc[3][0] = fmaf(a.w, w.x, acc[3][0]);
        acc[3][1] = fmaf(a.w, w.y, acc[3][1]);
        acc[3][2] = fmaf(a.w, w.z, acc[3][2]);
        acc[3][3] = fmaf(a.w, w.w, acc[3][3]);
    }
    __syncthreads();  // smem reuse: A-tile -> out-tile

    float4 bj = *(const float4*)&bias[j0];
#pragma unroll
    for (int i = 0; i < 4; ++i) {
        float4 o;
        o.x = acc[i][0] + bj.x;
        o.y = acc[i][1] + bj.y;
        o.z = acc[i][2] + bj.z;
        o.w = acc[i][3] + bj.w;
        *(float4*)&smem[(nn0 + i) * OSTR + j0] = o;
    }
    __syncthreads();

    // LayerNorm: one wave per node
    int wid = tid >> 6, lane = tid & 63;
    for (int nn = wid; nn < TN; nn += 4) {
        int node = n0base + nn;
        if (node >= n) continue;
        float v0 = smem[nn * OSTR + lane];
        float v1 = (DOUT == 128) ? smem[nn * OSTR + 64 + lane] : 0.f;
        float s = v0 + v1;
        float ss = v0 * v0 + v1 * v1;
#pragma unroll
        for (int off = 32; off > 0; off >>= 1) {
            s += __shfl_xor(s, off);
            ss += __shfl_xor(ss, off);
        }
        float mu = s / DOUT;
        float var = ss / DOUT - mu * mu;
        float inv = rsqrtf(var + EPS);
        float y0 = (v0 - mu) * inv * g[lane] + be[lane];
        if (RELU) y0 = fmaxf(y0, 0.f);
        out[(size_t)node * DOUT + lane] = y0;
        if (DOUT == 128) {
            float y1 = (v1 - mu) * inv * g[64 + lane] + be[64 + lane];
            if (RELU) y1 = fmaxf(y1, 0.f);
            out[(size_t)node * DOUT + 64 + lane] = y1;
        }
    }
}

extern "C" void kernel_launch(void* const* d_in, const int* in_sizes, int n_in,
                              void* d_out, int out_size, void* d_ws, size_t ws_size,
                              hipStream_t stream) {
    const float* x = (const float*)d_in[0];
    const int* edge = (const int*)d_in[1];
    int E = in_sizes[1] / 2;
    const int* src = edge;
    const int* dst = edge + E;

    const float* w1l = (const float*)d_in[2];
    const float* b1  = (const float*)d_in[3];
    const float* w1r = (const float*)d_in[4];
    const float* g1  = (const float*)d_in[5];
    const float* be1 = (const float*)d_in[6];
    const float* w2l = (const float*)d_in[7];
    const float* b2  = (const float*)d_in[8];
    const float* w2r = (const float*)d_in[9];
    const float* g2  = (const float*)d_in[10];
    const float* be2 = (const float*)d_in[11];
    const float* w3l = (const float*)d_in[12];
    const float* b3  = (const float*)d_in[13];
    const float* w3r = (const float*)d_in[14];
    const float* g3  = (const float*)d_in[15];
    const float* be3 = (const float*)d_in[16];
    const float* w4l = (const float*)d_in[17];
    const float* b4  = (const float*)d_in[18];
    const float* w4r = (const float*)d_in[19];
    const float* g4  = (const float*)d_in[20];
    const float* be4 = (const float*)d_in[21];

    char* ws = (char*)d_ws;
    size_t off = 0;
    auto alloc = [&](size_t bytes) {
        void* p = ws + off;
        off = (off + bytes + 255) & ~(size_t)255;
        return p;
    };
    int* row_ptr = (int*)alloc((N_NODES + 1) * sizeof(int));
    int* cnt     = (int*)alloc(N_NODES * sizeof(int));
    int* fill    = (int*)alloc(N_NODES * sizeof(int));
    int* bsum    = (int*)alloc(512 * sizeof(int));
    int* bpre    = (int*)alloc(512 * sizeof(int));
    int* colx    = (int*)alloc((size_t)E * sizeof(int));
    float* wt1   = (float*)alloc(18 * 64 * sizeof(float));
    float* wt2   = (float*)alloc(128 * 128 * sizeof(float));
    float* wt3   = (float*)alloc(256 * 128 * sizeof(float));
    float* wt4   = (float*)alloc(256 * 128 * sizeof(float));
    float* meanb = (float*)alloc((size_t)N_NODES * 128 * sizeof(float));
    float* ha    = (float*)alloc((size_t)N_NODES * 128 * sizeof(float));
    float* hb    = (float*)alloc((size_t)N_NODES * 128 * sizeof(float));
    (void)ws_size;

    hipMemsetAsync(cnt, 0, N_NODES * sizeof(int), stream);
    hipMemsetAsync(fill, 0, N_NODES * sizeof(int), stream);

    int EB = (E + 255) / 256;
    hist_kernel<<<EB, 256, 0, stream>>>(dst, E, cnt);
    int NB = (N_NODES + 255) / 256;  // 391
    scan1_kernel<<<NB, 256, 0, stream>>>(cnt, N_NODES, bsum);
    scan2_kernel<<<1, 512, 0, stream>>>(bsum, NB, bpre, row_ptr, N_NODES, E);
    scan3_kernel<<<NB, 256, 0, stream>>>(cnt, N_NODES, bpre, row_ptr);
    scatter_kernel<<<EB, 256, 0, stream>>>(src, dst, E, row_ptr, fill, colx);

    wtrans_kernel<<<(18 * 64 + 255) / 256, 256, 0, stream>>>(w1l, w1r, 9, 64, wt1);
    wtrans_kernel<<<(128 * 128 + 255) / 256, 256, 0, stream>>>(w2l, w2r, 64, 128, wt2);
    wtrans_kernel<<<(256 * 128 + 255) / 256, 256, 0, stream>>>(w3l, w3r, 128, 128, wt3);
    wtrans_kernel<<<(256 * 128 + 255) / 256, 256, 0, stream>>>(w4l, w4r, 128, 128, wt4);

    float* out = (float*)d_out;
    int AGB = (N_NODES * 64 + 255) / 256;  // one wave per node

    // layer 1: 9 -> 64
    agg_kernel<9><<<AGB, 256, 0, stream>>>(x, row_ptr, colx, meanb, N_NODES);
    linear_ln_kernel<9, 64, true><<<(N_NODES + 63) / 64, 256, 0, stream>>>(
        meanb, x, wt1, b1, g1, be1, ha, N_NODES);
    // layer 2: 64 -> 128
    agg_kernel<64><<<AGB, 256, 0, stream>>>(ha, row_ptr, colx, meanb, N_NODES);
    linear_ln_kernel<64, 128, true><<<(N_NODES + 31) / 32, 256, 0, stream>>>(
        meanb, ha, wt2, b2, g2, be2, hb, N_NODES);
    // layer 3: 128 -> 128
    agg_kernel<128><<<AGB, 256, 0, stream>>>(hb, row_ptr, colx, meanb, N_NODES);
    linear_ln_kernel<128, 128, true><<<(N_NODES + 31) / 32, 256, 0, stream>>>(
        meanb, hb, wt3, b3, g3, be3, ha, N_NODES);
    // layer 4: 128 -> 128 (no ReLU)
    agg_kernel<128><<<AGB, 256, 0, stream>>>(ha, row_ptr, colx, meanb, N_NODES);
    linear_ln_kernel<128, 128, false><<<(N_NODES + 31) / 32, 256, 0, stream>>>(
        meanb, ha, wt4, b4, g4, be4, out, N_NODES);
}

// Round 2
// 586.435 us; speedup vs baseline: 1.6677x; 1.6677x over previous
//
#include <hip/hip_runtime.h>
#include <hip/hip_bf16.h>
#include <math.h>

#define N_NODES 100000
#define EPS 1e-5f

typedef __attribute__((ext_vector_type(8))) short bf16x8;
typedef __attribute__((ext_vector_type(4))) float f32x4;

__device__ __forceinline__ float bflo(unsigned int u) { return __uint_as_float(u << 16); }
__device__ __forceinline__ float bfhi(unsigned int u) { return __uint_as_float(u & 0xffff0000u); }
__device__ __forceinline__ unsigned short fbits(float f) {
    __hip_bfloat16 h = __float2bfloat16(f);
    return *reinterpret_cast<unsigned short*>(&h);
}
__device__ __forceinline__ void stv(float* p, float y) { *p = y; }
__device__ __forceinline__ void stv(__hip_bfloat16* p, float y) { *p = __float2bfloat16(y); }

// ---------------- CSR build ----------------
__global__ void hist_kernel(const int* __restrict__ dst, int E, int* __restrict__ cnt) {
    int e = blockIdx.x * blockDim.x + threadIdx.x;
    if (e < E) atomicAdd(&cnt[dst[e]], 1);
}

__global__ void scan1_kernel(const int* __restrict__ cnt, int n, int* __restrict__ bsum) {
    __shared__ int s[256];
    int i = blockIdx.x * 256 + threadIdx.x;
    s[threadIdx.x] = (i < n) ? cnt[i] : 0;
    __syncthreads();
    for (int off = 128; off > 0; off >>= 1) {
        if (threadIdx.x < off) s[threadIdx.x] += s[threadIdx.x + off];
        __syncthreads();
    }
    if (threadIdx.x == 0) bsum[blockIdx.x] = s[0];
}

__global__ void scan2_kernel(const int* __restrict__ bsum, int nb, int* __restrict__ bpre,
                             int* __restrict__ row_ptr, int n, int E) {
    __shared__ int s[512];
    int t = threadIdx.x;
    s[t] = (t < nb) ? bsum[t] : 0;
    __syncthreads();
    for (int off = 1; off < 512; off <<= 1) {
        int v = (t >= off) ? s[t - off] : 0;
        __syncthreads();
        s[t] += v;
        __syncthreads();
    }
    if (t < nb) bpre[t] = (t == 0) ? 0 : s[t - 1];
    if (t == 0) row_ptr[n] = E;
}

__global__ void scan3_kernel(const int* __restrict__ cnt, int n, const int* __restrict__ bpre,
                             int* __restrict__ row_ptr) {
    __shared__ int s[256];
    int i = blockIdx.x * 256 + threadIdx.x;
    int t = threadIdx.x;
    int v = (i < n) ? cnt[i] : 0;
    s[t] = v;
    __syncthreads();
    for (int off = 1; off < 256; off <<= 1) {
        int u = (t >= off) ? s[t - off] : 0;
        __syncthreads();
        s[t] += u;
        __syncthreads();
    }
    if (i < n) row_ptr[i] = bpre[blockIdx.x] + s[t] - v;
}

__global__ void scatter_kernel(const int* __restrict__ src, const int* __restrict__ dst, int E,
                               const int* __restrict__ row_ptr, int* __restrict__ fill,
                               int* __restrict__ col) {
    int e = blockIdx.x * blockDim.x + threadIdx.x;
    if (e < E) {
        int v = dst[e];
        int p = row_ptr[v] + atomicAdd(&fill[v], 1);
        col[p] = src[e];
    }
}

// ---------------- aggregation ----------------
// layer1: x fp32, d=9
__global__ void agg9_kernel(const float* __restrict__ h, const int* __restrict__ row_ptr,
                            const int* __restrict__ col, float* __restrict__ mean, int n) {
    int wid = (blockIdx.x * blockDim.x + threadIdx.x) >> 6;
    int lane = threadIdx.x & 63;
    if (wid >= n) return;
    int start = row_ptr[wid], end = row_ptr[wid + 1];
    float inv = 1.f / fmaxf((float)(end - start), 1.f);
    if (lane < 9) {
        float acc = 0.f;
        for (int p = start; p < end; ++p) acc += h[(size_t)col[p] * 9 + lane];
        mean[(size_t)wid * 9 + lane] = acc * inv;
    }
}

// bf16 d=64: one wave per node, lane = column
__global__ void agg64_kernel(const unsigned short* __restrict__ h, const int* __restrict__ row_ptr,
                             const int* __restrict__ col, unsigned short* __restrict__ mean, int n) {
    int wid = (blockIdx.x * blockDim.x + threadIdx.x) >> 6;
    int lane = threadIdx.x & 63;
    if (wid >= n) return;
    int start = row_ptr[wid], end = row_ptr[wid + 1];
    float inv = 1.f / fmaxf((float)(end - start), 1.f);
    float acc = 0.f;
    int p = start;
    for (; p + 4 <= end; p += 4) {
        int s0 = col[p], s1 = col[p + 1], s2 = col[p + 2], s3 = col[p + 3];
        acc += bflo((unsigned int)h[(size_t)s0 * 64 + lane] << 0 | 0u) * 0.f;  // placeholder avoided
        p = p;  // (rewritten below)
        break;
    }
    // simple unrolled loop (ushort loads, expand via bit shift)
    acc = 0.f;
    p = start;
    for (; p + 4 <= end; p += 4) {
        int s0 = col[p], s1 = col[p + 1], s2 = col[p + 2], s3 = col[p + 3];
        float a = __uint_as_float((unsigned int)h[(size_t)s0 * 64 + lane] << 16);
        float b = __uint_as_float((unsigned int)h[(size_t)s1 * 64 + lane] << 16);
        float c = __uint_as_float((unsigned int)h[(size_t)s2 * 64 + lane] << 16);
        float d = __uint_as_float((unsigned int)h[(size_t)s3 * 64 + lane] << 16);
        acc += a + b + c + d;
    }
    for (; p < end; ++p)
        acc += __uint_as_float((unsigned int)h[(size_t)col[p] * 64 + lane] << 16);
    mean[(size_t)wid * 64 + lane] = fbits(acc * inv);
}

// bf16 d=128: one wave per node, lane covers 2 columns (4B load)
__global__ void agg128_kernel(const unsigned short* __restrict__ h, const int* __restrict__ row_ptr,
                              const int* __restrict__ col, unsigned short* __restrict__ mean, int n) {
    int wid = (blockIdx.x * blockDim.x + threadIdx.x) >> 6;
    int lane = threadIdx.x & 63;
    if (wid >= n) return;
    int start = row_ptr[wid], end = row_ptr[wid + 1];
    float inv = 1.f / fmaxf((float)(end - start), 1.f);
    float ax = 0.f, ay = 0.f;
    int p = start;
    for (; p + 4 <= end; p += 4) {
        int s0 = col[p], s1 = col[p + 1], s2 = col[p + 2], s3 = col[p + 3];
        unsigned int u0 = *(const unsigned int*)&h[(size_t)s0 * 128 + lane * 2];
        unsigned int u1 = *(const unsigned int*)&h[(size_t)s1 * 128 + lane * 2];
        unsigned int u2 = *(const unsigned int*)&h[(size_t)s2 * 128 + lane * 2];
        unsigned int u3 = *(const unsigned int*)&h[(size_t)s3 * 128 + lane * 2];
        ax += bflo(u0) + bflo(u1) + bflo(u2) + bflo(u3);
        ay += bfhi(u0) + bfhi(u1) + bfhi(u2) + bfhi(u3);
    }
    for (; p < end; ++p) {
        unsigned int u = *(const unsigned int*)&h[(size_t)col[p] * 128 + lane * 2];
        ax += bflo(u);
        ay += bfhi(u);
    }
    unsigned int lo = fbits(ax * inv);
    unsigned int hi = fbits(ay * inv);
    *(unsigned int*)&mean[(size_t)wid * 128 + lane * 2] = lo | (hi << 16);
}

// ---------------- weight prep ----------------
// fp32 transpose for layer1: wt[k][j], k in [0,2*din)
__global__ void wtrans_kernel(const float* __restrict__ wl, const float* __restrict__ wr,
                              int din, int dout, float* __restrict__ wt) {
    int i = blockIdx.x * blockDim.x + threadIdx.x;
    int K2 = 2 * din;
    if (i >= K2 * dout) return;
    int k = i / dout, j = i % dout;
    wt[k * dout + j] = (k < din) ? wl[j * din + k] : wr[j * din + (k - din)];
}

// bf16 MFMA B-fragment pack: bpack[t][ks][lane][e], t=jtile(8), ks=kstep, lane 0..63, e 0..7
// B[k][j] fragment: j = t*16 + (lane&15), k = ks*32 + (lane>>4)*8 + e
__global__ void packw_kernel(const float* __restrict__ wl, const float* __restrict__ wr,
                             int din, unsigned short* __restrict__ bpack) {
    int K2 = 2 * din;
    int total = K2 * 128;
    int i = blockIdx.x * 256 + threadIdx.x;
    if (i >= total) return;
    int e = i & 7;
    int lane = (i >> 3) & 63;
    int rest = i >> 9;  // t * KSTEPS + ks
    int KSTEPS = din / 16;
    int t = rest / KSTEPS, ks = rest % KSTEPS;
    int j = t * 16 + (lane & 15);
    int k = ks * 32 + (lane >> 4) * 8 + e;
    float w = (k < din) ? wl[j * din + k] : wr[j * din + (k - din)];
    bpack[i] = fbits(w);
}

// ---------------- layer1 fp32 linear + LN + ReLU (templated output type) ----
template <int DIN, int DOUT, bool RELU, typename OT>
__global__ __launch_bounds__(256) void linear_ln_kernel(
    const float* __restrict__ meanp, const float* __restrict__ hp,
    const float* __restrict__ wt, const float* __restrict__ bias,
    const float* __restrict__ g, const float* __restrict__ be,
    OT* __restrict__ out, int n) {
    constexpr int K2 = 2 * DIN;
    constexpr int NCOL = DOUT / 4;
    constexpr int NROW = 256 / NCOL;
    constexpr int TN = 4 * NROW;
    constexpr int ASTR = TN + 4;
    constexpr int OSTR = DOUT + 4;
    constexpr int SMEMF = (K2 * ASTR > TN * OSTR) ? K2 * ASTR : TN * OSTR;
    __shared__ float smem[SMEMF];

    int tid = threadIdx.x;
    int n0base = blockIdx.x * TN;

    for (int idx = tid; idx < TN * K2; idx += 256) {
        int nn = idx / K2;
        int k = idx % K2;
        int node = n0base + nn;
        float v = 0.f;
        if (node < n)
            v = (k < DIN) ? meanp[(size_t)node * DIN + k] : hp[(size_t)node * DIN + (k - DIN)];
        smem[k * ASTR + nn] = v;
    }
    __syncthreads();

    int colt = tid % NCOL;
    int rowt = tid / NCOL;
    int j0 = colt * 4;
    int nn0 = rowt * 4;

    float acc[4][4];
#pragma unroll
    for (int i = 0; i < 4; ++i)
#pragma unroll
        for (int j = 0; j < 4; ++j) acc[i][j] = 0.f;

#pragma unroll 2
    for (int k = 0; k < K2; ++k) {
        float4 a = *(const float4*)&smem[k * ASTR + nn0];
        float4 w = *(const float4*)&wt[k * DOUT + j0];
        acc[0][0] = fmaf(a.x, w.x, acc[0][0]);
        acc[0][1] = fmaf(a.x, w.y, acc[0][1]);
        acc[0][2] = fmaf(a.x, w.z, acc[0][2]);
        acc[0][3] = fmaf(a.x, w.w, acc[0][3]);
        acc[1][0] = fmaf(a.y, w.x, acc[1][0]);
        acc[1][1] = fmaf(a.y, w.y, acc[1][1]);
        acc[1][2] = fmaf(a.y, w.z, acc[1][2]);
        acc[1][3] = fmaf(a.y, w.w, acc[1][3]);
        acc[2][0] = fmaf(a.z, w.x, acc[2][0]);
        acc[2][1] = fmaf(a.z, w.y, acc[2][1]);
        acc[2][2] = fmaf(a.z, w.z, acc[2][2]);
        acc[2][3] = fmaf(a.z, w.w, acc[2][3]);
        acc[3][0] = fmaf(a.w, w.x, acc[3][0]);
        acc[3][1] = fmaf(a.w, w.y, acc[3][1]);
        acc[3][2] = fmaf(a.w, w.z, acc[3][2]);
        acc[3][3] = fmaf(a.w, w.w, acc[3][3]);
    }
    __syncthreads();

    float4 bj = *(const float4*)&bias[j0];
#pragma unroll
    for (int i = 0; i < 4; ++i) {
        float4 o;
        o.x = acc[i][0] + bj.x;
        o.y = acc[i][1] + bj.y;
        o.z = acc[i][2] + bj.z;
        o.w = acc[i][3] + bj.w;
        *(float4*)&smem[(nn0 + i) * OSTR + j0] = o;
    }
    __syncthreads();

    int wid = tid >> 6, lane = tid & 63;
    for (int nn = wid; nn < TN; nn += 4) {
        int node = n0base + nn;
        if (node >= n) continue;
        float v0 = smem[nn * OSTR + lane];
        float v1 = (DOUT == 128) ? smem[nn * OSTR + 64 + lane] : 0.f;
        float s = v0 + v1;
        float ss = v0 * v0 + v1 * v1;
#pragma unroll
        for (int off = 32; off > 0; off >>= 1) {
            s += __shfl_xor(s, off);
            ss += __shfl_xor(ss, off);
        }
        float mu = s / DOUT;
        float var = ss / DOUT - mu * mu;
        float inv = rsqrtf(var + EPS);
        float y0 = (v0 - mu) * inv * g[lane] + be[lane];
        if (RELU) y0 = fmaxf(y0, 0.f);
        stv(&out[(size_t)node * DOUT + lane], y0);
        if (DOUT == 128) {
            float y1 = (v1 - mu) * inv * g[64 + lane] + be[64 + lane];
            if (RELU) y1 = fmaxf(y1, 0.f);
            stv(&out[(size_t)node * DOUT + 64 + lane], y1);
        }
    }
}

// ---------------- bf16 MFMA linear (concat-K) + LN + optional ReLU ----------
// Block: 256 threads = 4 waves; wave w handles 16 nodes; block = 64 nodes x 128 out.
// A frag: row = lane&15 (node), k = ks*32 + (lane>>4)*8 + e (contiguous from bf16 row)
// B frag: pre-packed. C/D: col = lane&15, row = (lane>>4)*4 + reg   [m89-verified]
template <int DIN, bool RELU, typename OT>
__global__ __launch_bounds__(256) void mfma_linear_ln(
    const unsigned short* __restrict__ meanb,  // [n][DIN] bf16
    const unsigned short* __restrict__ hb,     // [n][DIN] bf16
    const unsigned short* __restrict__ bpack,  // packed B frags
    const float* __restrict__ bias, const float* __restrict__ g,
    const float* __restrict__ be, OT* __restrict__ out, int n) {
    constexpr int KSTEPS = DIN / 16;  // K2/32
    int tid = threadIdx.x;
    int w = tid >> 6, l = tid & 63;
    int n0 = blockIdx.x * 64 + w * 16;
    int arow = l & 15;
    int koff = (l >> 4) * 8;
    int anode = n0 + arow;
    if (anode >= n) anode = n - 1;
    const unsigned short* mrow = meanb + (size_t)anode * DIN;
    const unsigned short* hrow = hb + (size_t)anode * DIN;

    f32x4 acc[8];
#pragma unroll
    for (int t = 0; t < 8; ++t) acc[t] = (f32x4){0.f, 0.f, 0.f, 0.f};

#pragma unroll
    for (int ks = 0; ks < KSTEPS; ++ks) {
        int k = ks * 32 + koff;
        const unsigned short* ap = (k < DIN) ? (mrow + k) : (hrow + (k - DIN));
        bf16x8 a = *(const bf16x8*)ap;
#pragma unroll
        for (int t = 0; t < 8; ++t) {
            bf16x8 b = *(const bf16x8*)(bpack + (((size_t)t * KSTEPS + ks) * 64 + l) * 8);
            acc[t] = __builtin_amdgcn_mfma_f32_16x16x32_bf16(a, b, acc[t], 0, 0, 0);
        }
    }

    int jbase = l & 15;
    float bj[8], gj[8], bej[8];
#pragma unroll
    for (int t = 0; t < 8; ++t) {
        bj[t] = bias[t * 16 + jbase];
        gj[t] = g[t * 16 + jbase];
        bej[t] = be[t * 16 + jbase];
    }
#pragma unroll
    for (int r = 0; r < 4; ++r) {
        float v[8];
        float s = 0.f, ss = 0.f;
#pragma unroll
        for (int t = 0; t < 8; ++t) {
            v[t] = acc[t][r] + bj[t];
            s += v[t];
            ss += v[t] * v[t];
        }
#pragma unroll
        for (int off = 1; off < 16; off <<= 1) {
            s += __shfl_xor(s, off);
            ss += __shfl_xor(ss, off);
        }
        float mu = s * (1.f / 128.f);
        float var = ss * (1.f / 128.f) - mu * mu;
        float inv = rsqrtf(var + EPS);
        int node = n0 + (l >> 4) * 4 + r;
        if (node < n) {
#pragma unroll
            for (int t = 0; t < 8; ++t) {
                float y = (v[t] - mu) * inv * gj[t] + bej[t];
                if (RELU) y = fmaxf(y, 0.f);
                stv(&out[(size_t)node * 128 + t * 16 + jbase], y);
            }
        }
    }
}

extern "C" void kernel_launch(void* const* d_in, const int* in_sizes, int n_in,
                              void* d_out, int out_size, void* d_ws, size_t ws_size,
                              hipStream_t stream) {
    const float* x = (const float*)d_in[0];
    const int* edge = (const int*)d_in[1];
    int E = in_sizes[1] / 2;
    const int* src = edge;
    const int* dst = edge + E;

    const float* w1l = (const float*)d_in[2];
    const float* b1  = (const float*)d_in[3];
    const float* w1r = (const float*)d_in[4];
    const float* g1  = (const float*)d_in[5];
    const float* be1 = (const float*)d_in[6];
    const float* w2l = (const float*)d_in[7];
    const float* b2  = (const float*)d_in[8];
    const float* w2r = (const float*)d_in[9];
    const float* g2  = (const float*)d_in[10];
    const float* be2 = (const float*)d_in[11];
    const float* w3l = (const float*)d_in[12];
    const float* b3  = (const float*)d_in[13];
    const float* w3r = (const float*)d_in[14];
    const float* g3  = (const float*)d_in[15];
    const float* be3 = (const float*)d_in[16];
    const float* w4l = (const float*)d_in[17];
    const float* b4  = (const float*)d_in[18];
    const float* w4r = (const float*)d_in[19];
    const float* g4  = (const float*)d_in[20];
    const float* be4 = (const float*)d_in[21];

    char* ws = (char*)d_ws;
    size_t off = 0;
    auto alloc = [&](size_t bytes) {
        void* p = ws + off;
        off = (off + bytes + 255) & ~(size_t)255;
        return p;
    };
    int* row_ptr = (int*)alloc((N_NODES + 1) * sizeof(int));
    int* cnt     = (int*)alloc(N_NODES * sizeof(int));
    int* fill    = (int*)alloc(N_NODES * sizeof(int));
    int* bsum    = (int*)alloc(512 * sizeof(int));
    int* bpre    = (int*)alloc(512 * sizeof(int));
    int* colx    = (int*)alloc((size_t)E * sizeof(int));
    float* wt1   = (float*)alloc(18 * 64 * sizeof(float));
    unsigned short* bp2 = (unsigned short*)alloc(128 * 128 * sizeof(short));
    unsigned short* bp3 = (unsigned short*)alloc(256 * 128 * sizeof(short));
    unsigned short* bp4 = (unsigned short*)alloc(256 * 128 * sizeof(short));
    float* m9    = (float*)alloc((size_t)N_NODES * 9 * sizeof(float));
    unsigned short* mbf = (unsigned short*)alloc((size_t)N_NODES * 128 * sizeof(short));
    unsigned short* h1  = (unsigned short*)alloc((size_t)N_NODES * 64 * sizeof(short));
    unsigned short* h2  = (unsigned short*)alloc((size_t)N_NODES * 128 * sizeof(short));
    unsigned short* h3  = (unsigned short*)alloc((size_t)N_NODES * 128 * sizeof(short));
    (void)ws_size;

    hipMemsetAsync(cnt, 0, N_NODES * sizeof(int), stream);
    hipMemsetAsync(fill, 0, N_NODES * sizeof(int), stream);

    int EB = (E + 255) / 256;
    hist_kernel<<<EB, 256, 0, stream>>>(dst, E, cnt);
    int NB = (N_NODES + 255) / 256;  // 391
    scan1_kernel<<<NB, 256, 0, stream>>>(cnt, N_NODES, bsum);
    scan2_kernel<<<1, 512, 0, stream>>>(bsum, NB, bpre, row_ptr, N_NODES, E);
    scan3_kernel<<<NB, 256, 0, stream>>>(cnt, N_NODES, bpre, row_ptr);
    scatter_kernel<<<EB, 256, 0, stream>>>(src, dst, E, row_ptr, fill, colx);

    wtrans_kernel<<<(18 * 64 + 255) / 256, 256, 0, stream>>>(w1l, w1r, 9, 64, wt1);
    packw_kernel<<<(128 * 128 + 255) / 256, 256, 0, stream>>>(w2l, w2r, 64, bp2);
    packw_kernel<<<(256 * 128 + 255) / 256, 256, 0, stream>>>(w3l, w3r, 128, bp3);
    packw_kernel<<<(256 * 128 + 255) / 256, 256, 0, stream>>>(w4l, w4r, 128, bp4);

    float* out = (float*)d_out;
    int AGB = (N_NODES * 64 + 255) / 256;  // one wave per node
    int LNB = (N_NODES + 63) / 64;         // 64 nodes per block

    // layer 1: 9 -> 64 (fp32 compute, bf16 out)
    agg9_kernel<<<AGB, 256, 0, stream>>>(x, row_ptr, colx, m9, N_NODES);
    linear_ln_kernel<9, 64, true, __hip_bfloat16><<<LNB, 256, 0, stream>>>(
        m9, x, wt1, b1, g1, be1, (__hip_bfloat16*)h1, N_NODES);
    // layer 2: 64 -> 128
    agg64_kernel<<<AGB, 256, 0, stream>>>(h1, row_ptr, colx, mbf, N_NODES);
    mfma_linear_ln<64, true, __hip_bfloat16><<<LNB, 256, 0, stream>>>(
        mbf, h1, bp2, b2, g2, be2, (__hip_bfloat16*)h2, N_NODES);
    // layer 3: 128 -> 128
    agg128_kernel<<<AGB, 256, 0, stream>>>(h2, row_ptr, colx, mbf, N_NODES);
    mfma_linear_ln<128, true, __hip_bfloat16><<<LNB, 256, 0, stream>>>(
        mbf, h2, bp3, b3, g3, be3, (__hip_bfloat16*)h3, N_NODES);
    // layer 4: 128 -> 128 (no ReLU, fp32 out)
    agg128_kernel<<<AGB, 256, 0, stream>>>(h3, row_ptr, colx, mbf, N_NODES);
    mfma_linear_ln<128, false, float><<<LNB, 256, 0, stream>>>(
        mbf, h3, bp4, b4, g4, be4, out, N_NODES);
}